// Round 4
// baseline (277.116 us; speedup 1.0000x reference)
//
#include <hip/hip_runtime.h>
#include <math.h>

#define BINS 30

static constexpr int BLOCK  = 256;
static constexpr int GRID   = 1024;  // 4 resident blocks/CU (33 KiB LDS) x 256 CUs
static constexpr int SLOTS  = 32;    // 30 bins + slot 30 = trash (out-of-range), 31 pad
static constexpr int UNROLL = 4;     // float4 loads per array per chunk (8 KiB/wave per burst)

typedef float f32x4 __attribute__((ext_vector_type(4)));

__device__ __forceinline__ float wave_sum(float v) {
    #pragma unroll
    for (int o = 32; o > 0; o >>= 1) v += __shfl_xor(v, o, 64);
    return v;
}

// Per-thread private packed histograms in LDS: h[slot*256 + tid] holds
// x-count in bits 0..15 (+1), y-count in bits 16..31 (+65536).
// ds_add_u32 fire-and-forget; columns thread-private, bank = tid%32,
// 2-way within wave = free (m136). SQ_LDS_BANK_CONFLICT = 0 verified.
//
// R8 post-mortem chain:
//  - R2 forensics: hist dispatches with inputs FULLY L3-RESIDENT (hbm_bytes
//    ~0.3 MB) ran at the SAME 93.5 us as HBM-fed ones -> speed independent
//    of data source -> NOT bandwidth-bound; the nontemporal (L2-bypass)
//    request path itself caps per-CU streaming at ~4.6 B/cyc.
//  - R3 ping-pong was neutral -> either NT is the cap, or the scheduler
//    sank the prefetch burst below the consume (nothing pinned issue order).
// R4 therefore: (1) drop the NT hint -- zero reuse means L2 pollution is
// irrelevant, and the 6.3 TB/s copy ceiling (m13) was measured with regular
// loads; (2) pin the prefetch with sched_barrier(0) right after each LOAD
// burst so the 8 next-chunk loads are issued before the consume (counted
// vmcnt waits, T4 idiom).
// Exactness: per-thread per-slot x-count <= 128 < 2^16; per-block per-slot
// column sum <= 32768 < 2^16 -> packed u32 sums exact.
__global__ __launch_bounds__(BLOCK, 4) void hist_kernel(
        const float* __restrict__ x, const float* __restrict__ y,
        int n4, unsigned int* __restrict__ g_hist)
{
    __shared__ unsigned int h[SLOTS * BLOCK];     // 32 KiB
    __shared__ unsigned int partial[BLOCK];       // +1 KiB
    const int tid = threadIdx.x;

    #pragma unroll
    for (int i = 0; i < SLOTS; ++i) h[i * BLOCK + tid] = 0u;
    __syncthreads();

    const f32x4* __restrict__ x4 = (const f32x4*)x;
    const f32x4* __restrict__ y4 = (const f32x4*)y;

    // torch.histc: idx = floor((v+4)*3.75) clipped to [0,29]; |v|>4 (or NaN) -> trash slot 30
    #define PROC(v, inc) {                                              \
        float q = fmaf((v), 3.75f, 15.0f);                              \
        int idx = (int)q;                                               \
        idx = idx > 29 ? 29 : idx;        /* v == 4.0 -> last bin */    \
        bool valid = fabsf(v) <= 4.0f;                                  \
        int slot = valid ? idx : 30;                                    \
        atomicAdd(&h[slot * BLOCK + tid], (inc));  /* ds_add_u32 */     \
    }
    #define PROC4(f, inc) { PROC((f).x, inc) PROC((f).y, inc) PROC((f).z, inc) PROC((f).w, inc) }

    // Ping-pong register buffers -- names static, never runtime-indexed.
    f32x4 aA[UNROLL], bA[UNROLL], aB[UNROLL], bB[UNROLL];

    #define LOAD(S, c) {                                                     \
        _Pragma("unroll")                                                    \
        for (int j = 0; j < UNROLL; ++j) {                                   \
            a##S[j] = x4[(c) + j * BLOCK + tid];   /* regular cached load */ \
            b##S[j] = y4[(c) + j * BLOCK + tid];                             \
        } }
    #define CONSUME(S) {                                                     \
        _Pragma("unroll")                                                    \
        for (int j = 0; j < UNROLL; ++j) {                                   \
            PROC4(a##S[j], 1u)                                               \
            PROC4(b##S[j], 65536u)                                           \
        } }

    const int span    = GRID * BLOCK * UNROLL;   // float4 stride per chunk step
    const int iter_sz = BLOCK * UNROLL;
    const int nfull   = n4 / span;               // complete spans (8 for the bench)

    if (nfull > 0) {
        int c = blockIdx.x * iter_sz;
        int done = 0;
        LOAD(A, c)
        for (;;) {
            if (done + 1 < nfull) {
                LOAD(B, c + span)                       // 8 loads in flight...
                __builtin_amdgcn_sched_barrier(0);      // ...pinned above consume
            }
            CONSUME(A)
            if (++done >= nfull) break;
            if (done + 1 < nfull) {
                LOAD(A, c + 2 * span)
                __builtin_amdgcn_sched_barrier(0);
            }
            CONSUME(B)
            if (++done >= nfull) break;
            c += 2 * span;
        }
    }

    // Tail: grid-stride over the residue region (empty for the benchmark).
    for (int i = nfull * span + blockIdx.x * BLOCK + tid; i < n4; i += GRID * BLOCK) {
        f32x4 a = x4[i], b = y4[i];
        PROC4(a, 1u)
        PROC4(b, 65536u)
    }
    #undef CONSUME
    #undef LOAD
    #undef PROC4
    #undef PROC
    __syncthreads();

    // Reduce 256 columns per slot (packed u32 sums exact).
    const int slot = tid & 31;
    const int c0   = (tid >> 5) * 32;
    unsigned int s = 0;
    #pragma unroll 8
    for (int c = 0; c < 32; ++c) {
        int col = c0 + ((c + tid) & 31);
        s += h[slot * BLOCK + col];
    }
    partial[tid] = s;
    __syncthreads();
    if (tid < 32) {
        unsigned int tot = 0;
        #pragma unroll
        for (int g = 0; g < 8; ++g) tot += partial[g * 32 + tid];
        if (tid < BINS) {
            atomicAdd(&g_hist[tid],      tot & 0xFFFFu);  // x histogram
            atomicAdd(&g_hist[32 + tid], tot >> 16);      // y histogram
        }
    }
}

__global__ void finalize_kernel(const unsigned int* __restrict__ g_hist,
                                float* __restrict__ out)
{
    const int t = threadIdx.x;
    const bool active = t < BINS;
    float hx = active ? (float)g_hist[t]      : 0.0f;
    float hy = active ? (float)g_hist[32 + t] : 0.0f;
    float hj = hx + hy;                      // joint = hist_x + hist_y exactly

    float Sx = wave_sum(hx);
    float Sy = wave_sum(hy);
    float Sj = wave_sum(hj);

    float px = hx / Sx;
    float py = hy / Sy;
    float jp = hj / Sj;

    // mi = 30 * sum_j jp_j*(log jp_j - log py_j) - (sum_j jp_j) * (sum_i log px_i)
    float term = active ? jp * (logf(jp) - logf(py)) : 0.0f;
    float lpx  = active ? logf(px) : 0.0f;
    float sjp  = wave_sum(active ? jp : 0.0f);

    float st = wave_sum(term);
    float sl = wave_sum(lpx);
    if (t == 0) out[0] = -((float)BINS * st - sjp * sl);
}

extern "C" void kernel_launch(void* const* d_in, const int* in_sizes, int n_in,
                              void* d_out, int out_size, void* d_ws, size_t ws_size,
                              hipStream_t stream) {
    const float* x = (const float*)d_in[0];
    const float* y = (const float*)d_in[1];
    const int n = in_sizes[0];               // 2^25, divisible by 4
    unsigned int* g_hist = (unsigned int*)d_ws;

    (void)hipMemsetAsync(d_ws, 0, 64 * sizeof(unsigned int), stream);  // ws is poisoned 0xAA
    hist_kernel<<<GRID, BLOCK, 0, stream>>>(x, y, n >> 2, g_hist);
    finalize_kernel<<<1, 64, 0, stream>>>(g_hist, (float*)d_out);
}